// Round 3
// 412.960 us; speedup vs baseline: 1.0021x; 1.0021x over previous
//
#include <hip/hip_runtime.h>
#include <math.h>

typedef __bf16 bf16x8 __attribute__((ext_vector_type(8)));
typedef float f32x4 __attribute__((ext_vector_type(4)));

#define MFMA_BF16(a,b,c) __builtin_amdgcn_mfma_f32_16x16x32_bf16((a),(b),(c),0,0,0)

static constexpr int S_LEN = 2048;
static constexpr int DM    = 2048;
static constexpr int NHEAD = 16;
static constexpr int LDH   = 128;
static constexpr int BATCH = 2;
static constexpr size_t QKV_SEG = (size_t)BATCH * NHEAD * S_LEN * LDH;  // elems per q/k/v

__device__ __forceinline__ unsigned short f2bf(float f) {
    unsigned u = __float_as_uint(f);
    u += 0x7fffu + ((u >> 16) & 1u);
    return (unsigned short)(u >> 16);
}
__device__ __forceinline__ float bf2f(unsigned short h) {
    return __uint_as_float(((unsigned)h) << 16);
}
__device__ __forceinline__ float fexp2(float x) { return exp2f(x); }

__device__ __forceinline__ void ld_lds16(const void* g, void* l) {
    __builtin_amdgcn_global_load_lds(
        (const __attribute__((address_space(1))) unsigned int*)g,
        (__attribute__((address_space(3))) unsigned int*)l, 16, 0, 0);
}

// ---------------- fp32 -> bf16 elementwise (x) ----------------
__global__ void convert_f32_bf16(const float* __restrict__ in,
                                 unsigned short* __restrict__ out, int n4) {
    int idx = blockIdx.x * blockDim.x + threadIdx.x;
    if (idx >= n4) return;
    float4 v = reinterpret_cast<const float4*>(in)[idx];
    unsigned lo = (unsigned)f2bf(v.x) | ((unsigned)f2bf(v.y) << 16);
    unsigned hi = (unsigned)f2bf(v.z) | ((unsigned)f2bf(v.w) << 16);
    reinterpret_cast<uint2*>(out)[idx] = make_uint2(lo, hi);
}

// ---------------- rope cos/sin tables: (S, 64) fp32 each ----------------
__global__ void gen_tab(float* __restrict__ ct, float* __restrict__ st) {
    int i = threadIdx.x & 63;
    int s = blockIdx.x * 4 + (threadIdx.x >> 6);
    float freq = (float)exp(-(double)(2 * i) / 128.0 * 9.210340371976184);
    float a = (float)s * freq;
    ct[s * 64 + i] = cosf(a);
    st[s * 64 + i] = sinf(a);
}

// ---------------- fp32 (K x N) -> bf16 transposed (N x K), 4 weights ----------------
__global__ void wconv_t4(const float* __restrict__ W0, const float* __restrict__ W1,
                         const float* __restrict__ W2, const float* __restrict__ W3,
                         unsigned short* __restrict__ O0, unsigned short* __restrict__ O1,
                         unsigned short* __restrict__ O2, unsigned short* __restrict__ O3) {
    __shared__ unsigned short tile[32][33];
    int z = blockIdx.z;
    const float* W = (z == 0) ? W0 : (z == 1) ? W1 : (z == 2) ? W2 : W3;
    unsigned short* Wt = (z == 0) ? O0 : (z == 1) ? O1 : (z == 2) ? O2 : O3;
    int n0 = blockIdx.x * 32;
    int k0 = blockIdx.y * 32;
    int t = threadIdx.x;
    int ir = t >> 3, ic = (t & 7) * 4;
    float4 v = *reinterpret_cast<const float4*>(&W[(size_t)(k0 + ir) * DM + n0 + ic]);
    tile[ir][ic + 0] = f2bf(v.x);
    tile[ir][ic + 1] = f2bf(v.y);
    tile[ir][ic + 2] = f2bf(v.z);
    tile[ir][ic + 3] = f2bf(v.w);
    __syncthreads();
    unsigned lo = (unsigned)tile[ic + 0][ir] | ((unsigned)tile[ic + 1][ir] << 16);
    unsigned hi = (unsigned)tile[ic + 2][ir] | ((unsigned)tile[ic + 3][ir] << 16);
    *reinterpret_cast<uint2*>(&Wt[(size_t)(n0 + ir) * DM + k0 + ic]) = make_uint2(lo, hi);
}

// ---------------- 128^2-tile bf16 GEMM, fp32 row-major out + bias (output proj) ----------------
__global__ __launch_bounds__(256, 2) void gemm_bf16_out(
    const unsigned short* __restrict__ A,
    const unsigned short* __restrict__ Bt,
    const float* __restrict__ b0,
    float* __restrict__ outp)
{
    const int K = DM;
    __shared__ __attribute__((aligned(16))) unsigned short smem[8192];
    unsigned short* As = smem;            // 128x32
    unsigned short* Bs = smem + 4096;     // 128x32
    int t = threadIdx.x;
    int m0 = blockIdx.y * 128, n0 = blockIdx.x * 128;
    int lane = t & 63, i16 = lane & 15, quad = lane >> 4;
    int w = t >> 6;
    int wm = (w >> 1) * 64, wn = (w & 1) * 64;

    f32x4 acc[4][4];
    const f32x4 z4 = {0.f, 0.f, 0.f, 0.f};
    for (int mi = 0; mi < 4; ++mi)
        for (int ni = 0; ni < 4; ++ni) acc[mi][ni] = z4;

    for (int kk = 0; kk < K; kk += 32) {
        __syncthreads();
#pragma unroll
        for (int j = 0; j < 2; ++j) {
            int off = j * 4096 + w * 1024 + lane * 16;
            int row = off >> 6;
            int g = ((off >> 4) & 3) ^ ((row >> 1) & 3);
            ld_lds16(&A [(size_t)(m0 + row) * K + kk + g * 8], (char*)As + off);
            ld_lds16(&Bt[(size_t)(n0 + row) * K + kk + g * 8], (char*)Bs + off);
        }
        __syncthreads();

        bf16x8 aF[4], bF[4];
#pragma unroll
        for (int mi = 0; mi < 4; ++mi) {
            int rA = wm + mi * 16 + i16;
            aF[mi] = *reinterpret_cast<const bf16x8*>(
                (const char*)As + rA * 64 + ((quad ^ ((rA >> 1) & 3)) * 16));
        }
#pragma unroll
        for (int ni = 0; ni < 4; ++ni) {
            int rB = wn + ni * 16 + i16;
            bF[ni] = *reinterpret_cast<const bf16x8*>(
                (const char*)Bs + rB * 64 + ((quad ^ ((rB >> 1) & 3)) * 16));
        }
#pragma unroll
        for (int mi = 0; mi < 4; ++mi)
#pragma unroll
            for (int ni = 0; ni < 4; ++ni)
                acc[mi][ni] = MFMA_BF16(aF[mi], bF[ni], acc[mi][ni]);
    }

    for (int mi = 0; mi < 4; ++mi) {
        for (int ni = 0; ni < 4; ++ni) {
            int nn = n0 + wn + ni * 16 + i16;
            float bv = b0[nn];
            for (int r = 0; r < 4; ++r) {
                int mm = m0 + wm + mi * 16 + quad * 4 + r;
                outp[(size_t)mm * DM + nn] = acc[mi][ni][r] + bv;
            }
        }
    }
}

// ---------------- 256^2-tile fused QKV GEMM: 4-deep ring, counted vmcnt ----------------
// M=4096, N=6144, K=2048. 512 threads = 8 waves (2M x 4N), per-wave 128x64 out.
// BK=32; LDS = 4 ring slots x (A 16KB | B 16KB) = 128KB. Stage runs 3 K-tiles
// ahead; steady-state wait is vmcnt(8) (2 K-tiles in flight across each barrier).
// Epilogue: q/k -> RoPE (+softmax scale on q), v -> transposed (B,H,Ld,S), via
// 128KB LDS bounce (256x256 bf16 fits exactly).
__global__ __launch_bounds__(512, 2) void gemm256_qkv(
    const unsigned short* __restrict__ A,
    const unsigned short* __restrict__ Bt,
    const float* __restrict__ b0, const float* __restrict__ b1,
    const float* __restrict__ b2,
    const float* __restrict__ ctab, const float* __restrict__ stab,
    unsigned short* __restrict__ outp)
{
    constexpr int K  = DM;
    constexpr int NT = K / 32;     // 64 K-tiles
    __shared__ __attribute__((aligned(16))) unsigned short smem[65536];  // 128 KB

    int t = threadIdx.x, lane = t & 63, w = t >> 6;
    int i16 = lane & 15, quad = lane >> 4;
    int wc = w & 3, wr = w >> 2;

    // XCD-bijective swizzle: 384 blocks = 8 XCDs x 48; each XCD gets a
    // 3-wide column band (3 B-panels = 3MB, fits 4MB XCD L2), A streamed.
    int flat = blockIdx.y * 24 + blockIdx.x;
    int xcd = flat & 7, r8 = flat >> 3;
    int nbx = xcd * 3 + (r8 >> 4);
    int nby = r8 & 15;
    int m0 = nby * 256, n0 = nbx * 256;

    // per-lane staging addresses (2 global_load_lds per matrix per K-tile per wave)
    const unsigned short* ga[2];
    const unsigned short* gb[2];
    int loff[2];
#pragma unroll
    for (int j = 0; j < 2; ++j) {
        int off = j * 8192 + w * 1024 + lane * 16;   // within 16KB tile
        int row = off >> 6;                           // 64B rows (32 bf16)
        int q = ((off >> 4) & 3) ^ ((row >> 1) & 3);  // pre-swizzled source chunk
        ga[j] = A  + (size_t)(m0 + row) * K + q * 8;
        gb[j] = Bt + (size_t)(n0 + row) * K + q * 8;
        loff[j] = off;
    }

    auto stage = [&](int slot, int kt) {
        char* base = (char*)smem + slot * 32768;
#pragma unroll
        for (int j = 0; j < 2; ++j) {
            ld_lds16(ga[j] + kt * 32, base + loff[j]);
            ld_lds16(gb[j] + kt * 32, base + 16384 + loff[j]);
        }
    };

    f32x4 acc[8][4];
    const f32x4 z4 = {0.f, 0.f, 0.f, 0.f};
#pragma unroll
    for (int mi = 0; mi < 8; ++mi)
#pragma unroll
        for (int ni = 0; ni < 4; ++ni) acc[mi][ni] = z4;

    auto compute = [&](int slot) {
        const char* Ab = (const char*)smem + slot * 32768;
        const char* Bb = Ab + 16384;
        bf16x8 bF[4];
#pragma unroll
        for (int ni = 0; ni < 4; ++ni) {
            int rB = wc * 64 + ni * 16 + i16;
            bF[ni] = *reinterpret_cast<const bf16x8*>(
                Bb + rB * 64 + ((quad ^ ((rB >> 1) & 3)) * 16));
        }
#pragma unroll
        for (int h = 0; h < 2; ++h) {
            bf16x8 aF[4];
#pragma unroll
            for (int mi = 0; mi < 4; ++mi) {
                int rA = wr * 128 + h * 64 + mi * 16 + i16;
                aF[mi] = *reinterpret_cast<const bf16x8*>(
                    Ab + rA * 64 + ((quad ^ ((rA >> 1) & 3)) * 16));
            }
            __builtin_amdgcn_s_setprio(1);
#pragma unroll
            for (int mi = 0; mi < 4; ++mi)
#pragma unroll
                for (int ni = 0; ni < 4; ++ni)
                    acc[h * 4 + mi][ni] = MFMA_BF16(aF[mi], bF[ni], acc[h * 4 + mi][ni]);
            __builtin_amdgcn_s_setprio(0);
        }
    };

    // prologue: K-tiles 0..2 into slots 0..2 (12 loads/wave); wait for K0
    stage(0, 0); stage(1, 1); stage(2, 2);
    asm volatile("s_waitcnt vmcnt(8)" ::: "memory");
    __builtin_amdgcn_s_barrier();
    asm volatile("" ::: "memory");

    // steady state: stage K(tt+3) into slot (tt-1)&3 (dead since last barrier);
    // end-of-tile wait keeps 8 loads (K tt+2, tt+3) in flight — never drains.
    for (int tt = 0; tt < NT - 3; ++tt) {
        stage((tt + 3) & 3, tt + 3);
        compute(tt & 3);
        asm volatile("s_waitcnt vmcnt(8)" ::: "memory");
        __builtin_amdgcn_s_barrier();
        asm volatile("" ::: "memory");
    }
    // tail: drain
    compute((NT - 3) & 3);
    asm volatile("s_waitcnt vmcnt(4)" ::: "memory");
    __builtin_amdgcn_s_barrier();
    asm volatile("" ::: "memory");
    compute((NT - 2) & 3);
    asm volatile("s_waitcnt vmcnt(0)" ::: "memory");
    __builtin_amdgcn_s_barrier();
    asm volatile("" ::: "memory");
    compute((NT - 1) & 3);
    __syncthreads();   // all LDS reads done; ring becomes Cs bounce

    // ---------------- epilogue ----------------
    unsigned short* Cs = smem;                 // 256x256 bf16 = 128KB
    int which = n0 >> 11;                      // 0=q 1=k 2=v (uniform per block)
    int hh0 = (n0 & 2047) >> 7;                // first of the 2 heads in this tile
    const float* bp = (which == 0) ? b0 : ((which == 1) ? b1 : b2);
    int segn = n0 & 2047;
    int bb = m0 >> 11, s0 = m0 & 2047;

    if (which == 2) {
        // store transposed (d, s), XOR-swizzled s-groups;
        // Cs = [2 heads][128 d][256 s], head stride 128*256 = 32768 shorts
        int htile = wc >> 1;
#pragma unroll
        for (int mi = 0; mi < 8; ++mi)
#pragma unroll
            for (int ni = 0; ni < 4; ++ni) {
                int dcol = wc * 64 + ni * 16 + i16;
                int d = dcol & 127;
                float bv = bp[segn + dcol];
#pragma unroll
                for (int r = 0; r < 4; ++r) {
                    int sl = wr * 128 + mi * 16 + quad * 4 + r;
                    Cs[htile * 32768 + d * 256 + (((sl >> 3) ^ (d & 31)) * 8) + (sl & 7)] =
                        f2bf(acc[mi][ni][r] + bv);
                }
            }
        __syncthreads();
        unsigned short* vout = outp + 2 * QKV_SEG;
#pragma unroll
        for (int it = 0; it < 16; ++it) {
            int idx = it * 512 + t;
            int ht2 = idx >> 12, rem = idx & 4095, d = rem >> 5, sg = rem & 31;
            uint4 v = *reinterpret_cast<const uint4*>(
                &Cs[ht2 * 32768 + d * 256 + ((sg ^ (d & 31)) * 8)]);
            size_t oidx = (((size_t)(bb * NHEAD + hh0 + ht2)) * LDH + d) * S_LEN + s0 + sg * 8;
            *reinterpret_cast<uint4*>(vout + oidx) = v;
        }
    } else {
        // q/k: bounce raw acc+bias, then RoPE on store
#pragma unroll
        for (int mi = 0; mi < 8; ++mi)
#pragma unroll
            for (int ni = 0; ni < 4; ++ni) {
                int nl = wc * 64 + ni * 16 + i16;
                float bv = bp[segn + nl];
#pragma unroll
                for (int r = 0; r < 4; ++r) {
                    int ml = wr * 128 + mi * 16 + quad * 4 + r;
                    Cs[ml * 256 + nl] = f2bf(acc[mi][ni][r] + bv);
                }
            }
        __syncthreads();
        // fold softmax scale (1/sqrt(128)) * log2(e) into q
        float qscale = (which == 0) ? (0.08838834764831845f * 1.4426950408889634f) : 1.0f;
        unsigned short* qout = outp + (size_t)which * QKV_SEG;
#pragma unroll
        for (int it = 0; it < 16; ++it) {
            int idx = it * 512 + t;
            int row = idx >> 5, u = idx & 31, ht2 = u >> 4, c16 = u & 15;
            int mm = m0 + row, ss = mm & 2047, bb2 = mm >> 11;
            int i8 = (c16 & 7) * 8;
            const unsigned short* crow = Cs + row * 256 + ht2 * 128 + i8 * 2;
            uint4 w0 = *reinterpret_cast<const uint4*>(crow);
            uint4 w1 = *reinterpret_cast<const uint4*>(crow + 8);
            unsigned pw[8] = {w0.x, w0.y, w0.z, w0.w, w1.x, w1.y, w1.z, w1.w};
            float4 cA = *reinterpret_cast<const float4*>(&ctab[ss * 64 + i8]);
            float4 cB = *reinterpret_cast<const float4*>(&ctab[ss * 64 + i8 + 4]);
            float4 sA = *reinterpret_cast<const float4*>(&stab[ss * 64 + i8]);
            float4 sB = *reinterpret_cast<const float4*>(&stab[ss * 64 + i8 + 4]);
            float cv[8] = {cA.x, cA.y, cA.z, cA.w, cB.x, cB.y, cB.z, cB.w};
            float sv[8] = {sA.x, sA.y, sA.z, sA.w, sB.x, sB.y, sB.z, sB.w};
            bool hi = (c16 >= 8);
            unsigned short ov[8];
#pragma unroll
            for (int j = 0; j < 8; ++j) {
                float xe = bf2f((unsigned short)(pw[j] & 0xffff));
                float xo = bf2f((unsigned short)(pw[j] >> 16));
                float o = hi ? (xe * sv[j] + xo * cv[j]) : (xe * cv[j] - xo * sv[j]);
                ov[j] = f2bf(o * qscale);
            }
            size_t oidx = (((size_t)(bb2 * NHEAD + hh0 + ht2)) * S_LEN + ss) * LDH + c16 * 8;
            *reinterpret_cast<uint4*>(qout + oidx) =
                *reinterpret_cast<const uint4*>(ov);
        }
    }
}

// ---------------- flash attention v4: double-buffered staging ----------------
// anti-causal (keep k >= q); no-max softmax (exp2, scale folded into q);
// 128 q/block, 4 waves x 32 q; 64-key chunks; 1 barrier per chunk with
// async prefetch of chunk i+1 overlapping compute of chunk i.
__global__ __launch_bounds__(256, 2) void attn_kernel(
    const unsigned short* __restrict__ q,
    const unsigned short* __restrict__ k,
    const unsigned short* __restrict__ vt,
    unsigned short* __restrict__ att)
{
    __shared__ __attribute__((aligned(16))) unsigned short Ks[2][64 * 128];
    __shared__ __attribute__((aligned(16))) unsigned short Vs[2][128 * 64];
    __shared__ __attribute__((aligned(16))) unsigned short Ps[4][32 * 64];

    int bid = blockIdx.x;
    int second = bid >> 8;
    int p = bid & 255;
    int xb = second ? (15 - (p >> 5)) : (p >> 5);
    int bh = p & 31;
    int b = bh >> 4, h = bh & (NHEAD - 1);
    int q0 = xb * 128;

    int t = threadIdx.x, w = t >> 6, lane = t & 63;
    int i16 = lane & 15, quad = lane >> 4;
    int qbase = q0 + w * 32;

    bf16x8 qf[2][4];
#pragma unroll
    for (int qs = 0; qs < 2; ++qs) {
        const unsigned short* qrow = q + ((size_t)bh * S_LEN + qbase + qs * 16 + i16) * LDH;
#pragma unroll
        for (int c = 0; c < 4; ++c)
            qf[qs][c] = *reinterpret_cast<const bf16x8*>(qrow + c * 32 + quad * 8);
    }

    const f32x4 z4 = {0.f, 0.f, 0.f, 0.f};
    f32x4 o[2][8];
#pragma unroll
    for (int qs = 0; qs < 2; ++qs)
#pragma unroll
        for (int dt = 0; dt < 8; ++dt) o[qs][dt] = z4;
    float l_i[2] = {0.f, 0.f};

    const unsigned short* kbh  = k  + (size_t)bh * S_LEN * LDH;
    const unsigned short* vtbh = vt + (size_t)bh * LDH * S_LEN;
    unsigned short* PsW = Ps[w];

    auto stage = [&](int buf, int kk0) {
#pragma unroll
        for (int j = 0; j < 4; ++j) {
            int off = j * 4096 + w * 1024 + lane * 16;
            int key = off >> 8;
            int gk = ((off >> 4) & 15) ^ (key & 15);
            ld_lds16(&kbh[(size_t)(kk0 + key) * LDH + gk * 8], (char*)Ks[buf] + off);
            int d = off >> 7;
            int gv = ((off >> 4) & 7) ^ (d & 7);
            ld_lds16(&vtbh[(size_t)d * S_LEN + kk0 + gv * 8], (char*)Vs[buf] + off);
        }
    };

    stage(0, q0);
    int nch = (S_LEN - q0) >> 6;
    for (int ci = 0; ci < nch; ++ci) {
        __syncthreads();   // drains this wave's vmcnt -> buf[ci&1] ready; guards buf reuse
        if (ci + 1 < nch) stage((ci + 1) & 1, q0 + (ci + 1) * 64);
        int kk0 = q0 + ci * 64;
        if (kk0 + 64 <= qbase) continue;   // wave fully masked
        const unsigned short* Kb = Ks[ci & 1];
        const unsigned short* Vb = Vs[ci & 1];

        // QK^T: A=K (m=key), B=Q (n=q)
        f32x4 s[2][4];
#pragma unroll
        for (int qs = 0; qs < 2; ++qs)
#pragma unroll
            for (int kn = 0; kn < 4; ++kn) s[qs][kn] = z4;
#pragma unroll
        for (int c = 0; c < 4; ++c) {
            bf16x8 kf[4];
#pragma unroll
            for (int kn = 0; kn < 4; ++kn) {
                int key = kn * 16 + i16;
                int gs = (c * 4 + quad) ^ (key & 15);
                kf[kn] = *reinterpret_cast<const bf16x8*>((const char*)Kb + key * 256 + gs * 16);
            }
#pragma unroll
            for (int qs = 0; qs < 2; ++qs)
#pragma unroll
                for (int kn = 0; kn < 4; ++kn)
                    s[qs][kn] = MFMA_BF16(kf[kn], qf[qs][c], s[qs][kn]);
        }

        bool diag = (kk0 < qbase + 32);
#pragma unroll
        for (int qs = 0; qs < 2; ++qs) {
            int q_local = qs * 16 + i16;
            int qg = qbase + q_local;
#pragma unroll
            for (int kn = 0; kn < 4; ++kn) {
                int keyb = kk0 + kn * 16 + quad * 4;
                float pv[4];
                if (diag) {
#pragma unroll
                    for (int r = 0; r < 4; ++r)
                        pv[r] = (keyb + r >= qg) ? fexp2(s[qs][kn][r]) : 0.f;
                } else {
#pragma unroll
                    for (int r = 0; r < 4; ++r) pv[r] = fexp2(s[qs][kn][r]);
                }
                l_i[qs] += (pv[0] + pv[1]) + (pv[2] + pv[3]);
                unsigned lo = (unsigned)f2bf(pv[0]) | ((unsigned)f2bf(pv[1]) << 16);
                unsigned hi = (unsigned)f2bf(pv[2]) | ((unsigned)f2bf(pv[3]) << 16);
                int g = (kn * 2 + (quad >> 1)) ^ (q_local & 7);
                char* addr = (char*)PsW + q_local * 128 + g * 16 + (quad & 1) * 8;
                *reinterpret_cast<uint2*>(addr) = make_uint2(lo, hi);
            }
        }

        // PV: A=P (m=q), B=Vt (n=d); Ps per-wave -> no barrier
#pragma unroll
        for (int hh = 0; hh < 2; ++hh) {
            bf16x8 pf[2];
#pragma unroll
            for (int qs = 0; qs < 2; ++qs) {
                int q_local = qs * 16 + i16;
                int g = (hh * 4 + quad) ^ (q_local & 7);
                pf[qs] = *reinterpret_cast<const bf16x8*>((const char*)PsW + q_local * 128 + g * 16);
            }
#pragma unroll
            for (int dt = 0; dt < 8; ++dt) {
                int d = dt * 16 + i16;
                int gv = (hh * 4 + quad) ^ (d & 7);
                bf16x8 vf = *reinterpret_cast<const bf16x8*>((const char*)Vb + d * 128 + gv * 16);
                o[0][dt] = MFMA_BF16(pf[0], vf, o[0][dt]);
                o[1][dt] = MFMA_BF16(pf[1], vf, o[1][dt]);
            }
        }
    }

#pragma unroll
    for (int qs = 0; qs < 2; ++qs) {
        float lr = l_i[qs];
        lr += __shfl_xor(lr, 16);
        lr += __shfl_xor(lr, 32);
        l_i[qs] = lr;
    }
#pragma unroll
    for (int qs = 0; qs < 2; ++qs) {
#pragma unroll
        for (int r = 0; r < 4; ++r) {
            float lv = __shfl(l_i[qs], quad * 4 + r);
            float inv = 1.0f / lv;
            int qrow = qbase + qs * 16 + quad * 4 + r;
            unsigned short* orow = att + ((size_t)b * S_LEN + qrow) * DM + h * LDH;
#pragma unroll
            for (int dt = 0; dt < 8; ++dt)
                orow[dt * 16 + i16] = f2bf(o[qs][dt][r] * inv);
        }
    }
}

// ---------------- launcher ----------------
extern "C" void kernel_launch(void* const* d_in, const int* in_sizes, int n_in,
                              void* d_out, int out_size, void* d_ws, size_t ws_size,
                              hipStream_t stream) {
    const float* x  = (const float*)d_in[0];
    const float* Wq = (const float*)d_in[2];
    const float* bq = (const float*)d_in[3];
    const float* Wk = (const float*)d_in[4];
    const float* bk = (const float*)d_in[5];
    const float* Wv = (const float*)d_in[6];
    const float* bv = (const float*)d_in[7];
    const float* Wo = (const float*)d_in[8];
    const float* bo = (const float*)d_in[9];

    char* ws = (char*)d_ws;
    unsigned short* xb  = (unsigned short*)(ws);                  // 16 MB
    unsigned short* Wqt = (unsigned short*)(ws + 16777216);       // QKV weights contiguous
    unsigned short* Wkt = (unsigned short*)(ws + 25165824);
    unsigned short* Wvt = (unsigned short*)(ws + 33554432);
    unsigned short* Wot = (unsigned short*)(ws + 41943040);
    unsigned short* qkv = (unsigned short*)(ws + 50331648);       // q | k | v^T, 16 MB each
    unsigned short* att = (unsigned short*)(ws + 100663296);
    float* ctab = (float*)(ws + 117440512);                       // 512 KB
    float* stab = (float*)(ws + 117964800);                       // 512 KB

    convert_f32_bf16<<<8192, 256, 0, stream>>>(x, xb, (BATCH * S_LEN * DM) / 4);
    gen_tab<<<512, 256, 0, stream>>>(ctab, stab);
    wconv_t4<<<dim3(64, 64, 4), 256, 0, stream>>>(Wq, Wk, Wv, Wo, Wqt, Wkt, Wvt, Wot);

    // fused QKV projection + RoPE + V-transpose: M=4096, N=6144, K=2048
    gemm256_qkv<<<dim3(24, 16), 512, 0, stream>>>(
        xb, Wqt, bq, bk, bv, ctab, stab, qkv);

    attn_kernel<<<512, 256, 0, stream>>>(qkv, qkv + QKV_SEG, qkv + 2 * QKV_SEG, att);

    // output projection: M=4096, N=2048, K=2048, fp32 out
    gemm_bf16_out<<<dim3(DM / 128, (BATCH * S_LEN) / 128), 256, 0, stream>>>(
        att, Wot, bo, (float*)d_out);
}

// Round 5
// 396.033 us; speedup vs baseline: 1.0449x; 1.0427x over previous
//
#include <hip/hip_runtime.h>
#include <math.h>

typedef __bf16 bf16x8 __attribute__((ext_vector_type(8)));
typedef float f32x4 __attribute__((ext_vector_type(4)));

#define MFMA_BF16(a,b,c) __builtin_amdgcn_mfma_f32_16x16x32_bf16((a),(b),(c),0,0,0)

static constexpr int S_LEN = 2048;
static constexpr int DM    = 2048;
static constexpr int NHEAD = 16;
static constexpr int LDH   = 128;
static constexpr int BATCH = 2;
static constexpr size_t QKV_SEG = (size_t)BATCH * NHEAD * S_LEN * LDH;  // elems per q/k/v

__device__ __forceinline__ unsigned short f2bf(float f) {
    unsigned u = __float_as_uint(f);
    u += 0x7fffu + ((u >> 16) & 1u);
    return (unsigned short)(u >> 16);
}
__device__ __forceinline__ float bf2f(unsigned short h) {
    return __uint_as_float(((unsigned)h) << 16);
}
__device__ __forceinline__ float fexp2(float x) { return exp2f(x); }

__device__ __forceinline__ void ld_lds16(const void* g, void* l) {
    __builtin_amdgcn_global_load_lds(
        (const __attribute__((address_space(1))) unsigned int*)g,
        (__attribute__((address_space(3))) unsigned int*)l, 16, 0, 0);
}

// ---------------- fp32 -> bf16 elementwise (x) ----------------
__global__ void convert_f32_bf16(const float* __restrict__ in,
                                 unsigned short* __restrict__ out, int n4) {
    int idx = blockIdx.x * blockDim.x + threadIdx.x;
    if (idx >= n4) return;
    float4 v = reinterpret_cast<const float4*>(in)[idx];
    unsigned lo = (unsigned)f2bf(v.x) | ((unsigned)f2bf(v.y) << 16);
    unsigned hi = (unsigned)f2bf(v.z) | ((unsigned)f2bf(v.w) << 16);
    reinterpret_cast<uint2*>(out)[idx] = make_uint2(lo, hi);
}

// ---------------- rope cos/sin tables: (S, 64) fp32 each ----------------
__global__ void gen_tab(float* __restrict__ ct, float* __restrict__ st) {
    int i = threadIdx.x & 63;
    int s = blockIdx.x * 4 + (threadIdx.x >> 6);
    float freq = (float)exp(-(double)(2 * i) / 128.0 * 9.210340371976184);
    float a = (float)s * freq;
    ct[s * 64 + i] = cosf(a);
    st[s * 64 + i] = sinf(a);
}

// ---------------- fp32 (K x N) -> bf16 transposed (N x K), 4 weights ----------------
__global__ void wconv_t4(const float* __restrict__ W0, const float* __restrict__ W1,
                         const float* __restrict__ W2, const float* __restrict__ W3,
                         unsigned short* __restrict__ O0, unsigned short* __restrict__ O1,
                         unsigned short* __restrict__ O2, unsigned short* __restrict__ O3) {
    __shared__ unsigned short tile[32][33];
    int z = blockIdx.z;
    const float* W = (z == 0) ? W0 : (z == 1) ? W1 : (z == 2) ? W2 : W3;
    unsigned short* Wt = (z == 0) ? O0 : (z == 1) ? O1 : (z == 2) ? O2 : O3;
    int n0 = blockIdx.x * 32;
    int k0 = blockIdx.y * 32;
    int t = threadIdx.x;
    int ir = t >> 3, ic = (t & 7) * 4;
    float4 v = *reinterpret_cast<const float4*>(&W[(size_t)(k0 + ir) * DM + n0 + ic]);
    tile[ir][ic + 0] = f2bf(v.x);
    tile[ir][ic + 1] = f2bf(v.y);
    tile[ir][ic + 2] = f2bf(v.z);
    tile[ir][ic + 3] = f2bf(v.w);
    __syncthreads();
    unsigned lo = (unsigned)tile[ic + 0][ir] | ((unsigned)tile[ic + 1][ir] << 16);
    unsigned hi = (unsigned)tile[ic + 2][ir] | ((unsigned)tile[ic + 3][ir] << 16);
    *reinterpret_cast<uint2*>(&Wt[(size_t)(n0 + ir) * DM + k0 + ic]) = make_uint2(lo, hi);
}

// ---------------- 128^2-tile bf16 GEMM, fp32 row-major out + bias (output proj) ----------------
__global__ __launch_bounds__(256, 2) void gemm_bf16_out(
    const unsigned short* __restrict__ A,
    const unsigned short* __restrict__ Bt,
    const float* __restrict__ b0,
    float* __restrict__ outp)
{
    const int K = DM;
    __shared__ __attribute__((aligned(16))) unsigned short smem[8192];
    unsigned short* As = smem;            // 128x32
    unsigned short* Bs = smem + 4096;     // 128x32
    int t = threadIdx.x;
    int m0 = blockIdx.y * 128, n0 = blockIdx.x * 128;
    int lane = t & 63, i16 = lane & 15, quad = lane >> 4;
    int w = t >> 6;
    int wm = (w >> 1) * 64, wn = (w & 1) * 64;

    f32x4 acc[4][4];
    const f32x4 z4 = {0.f, 0.f, 0.f, 0.f};
    for (int mi = 0; mi < 4; ++mi)
        for (int ni = 0; ni < 4; ++ni) acc[mi][ni] = z4;

    for (int kk = 0; kk < K; kk += 32) {
        __syncthreads();
#pragma unroll
        for (int j = 0; j < 2; ++j) {
            int off = j * 4096 + w * 1024 + lane * 16;
            int row = off >> 6;
            int g = ((off >> 4) & 3) ^ ((row >> 1) & 3);
            ld_lds16(&A [(size_t)(m0 + row) * K + kk + g * 8], (char*)As + off);
            ld_lds16(&Bt[(size_t)(n0 + row) * K + kk + g * 8], (char*)Bs + off);
        }
        __syncthreads();

        bf16x8 aF[4], bF[4];
#pragma unroll
        for (int mi = 0; mi < 4; ++mi) {
            int rA = wm + mi * 16 + i16;
            aF[mi] = *reinterpret_cast<const bf16x8*>(
                (const char*)As + rA * 64 + ((quad ^ ((rA >> 1) & 3)) * 16));
        }
#pragma unroll
        for (int ni = 0; ni < 4; ++ni) {
            int rB = wn + ni * 16 + i16;
            bF[ni] = *reinterpret_cast<const bf16x8*>(
                (const char*)Bs + rB * 64 + ((quad ^ ((rB >> 1) & 3)) * 16));
        }
#pragma unroll
        for (int mi = 0; mi < 4; ++mi)
#pragma unroll
            for (int ni = 0; ni < 4; ++ni)
                acc[mi][ni] = MFMA_BF16(aF[mi], bF[ni], acc[mi][ni]);
    }

    for (int mi = 0; mi < 4; ++mi) {
        for (int ni = 0; ni < 4; ++ni) {
            int nn = n0 + wn + ni * 16 + i16;
            float bv = b0[nn];
            for (int r = 0; r < 4; ++r) {
                int mm = m0 + wm + mi * 16 + quad * 4 + r;
                outp[(size_t)mm * DM + nn] = acc[mi][ni][r] + bv;
            }
        }
    }
}

// ---------------- 256x128-tile fused QKV GEMM: 3-deep ring, counted vmcnt ----------------
// M=4096, N=6144, K=2048. 256 threads = 4 waves (2M x 2N), per-wave 128x64 out
// (same per-wave shape/ratio as the 256^2 version: 12 ds_read_b128 : 32 MFMA).
// BK=32; LDS = 3 ring slots x (A 16KB | B 8KB) = 72KB -> 2 blocks/CU.
// Grid 48x16 = 768 blocks packs 512-block capacity with backfill (no half-idle
// round like the 384-block 256^2 version). Stage runs 2 K-tiles ahead;
// steady-state wait vmcnt(6) keeps 6 loads (1 K-tile) in flight across barriers.
// BN=128 = exactly one head -> round-0-verified 128-wide epilogues, rows x2.
__global__ __launch_bounds__(256, 2) void gemm_qkv_v2(
    const unsigned short* __restrict__ A,
    const unsigned short* __restrict__ Bt,
    const float* __restrict__ b0, const float* __restrict__ b1,
    const float* __restrict__ b2,
    const float* __restrict__ ctab, const float* __restrict__ stab,
    unsigned short* __restrict__ outp)
{
    constexpr int K  = DM;
    constexpr int NT = K / 32;     // 64 K-tiles
    constexpr int SLOT_B = 24576;  // bytes per ring slot (A 16KB + B 8KB)
    __shared__ __attribute__((aligned(16))) unsigned short smem[36864];  // 72 KB

    int t = threadIdx.x, lane = t & 63, w = t >> 6;
    int i16 = lane & 15, quad = lane >> 4;
    int wc = w & 1, wr = w >> 1;

    // XCD-bijective swizzle: 768 blocks = 8 XCDs x 96; each XCD owns a
    // 6-wide N band (6 B-panels = 3MB, fits 4MB XCD L2), A streamed.
    int flat = blockIdx.y * 48 + blockIdx.x;
    int xcd = flat & 7, r8 = flat >> 3;          // r8 in [0,96)
    int nbx = xcd * 6 + (r8 >> 4);
    int nby = r8 & 15;
    int m0 = nby * 256, n0 = nbx * 128;

    // per-thread staging addresses (A: 4 loads, B: 2 loads per K-tile)
    const unsigned short* ga[4];
    const unsigned short* gb[2];
    int loffA[4], loffB[2];
#pragma unroll
    for (int j = 0; j < 4; ++j) {
        int off = j * 4096 + t * 16;              // within 16KB A tile
        int row = off >> 6;                       // 64B rows (32 bf16)
        int g = ((off >> 4) & 3) ^ ((row >> 1) & 3);
        ga[j] = A + (size_t)(m0 + row) * K + g * 8;
        loffA[j] = off;
    }
#pragma unroll
    for (int j = 0; j < 2; ++j) {
        int off = j * 4096 + t * 16;              // within 8KB B tile
        int row = off >> 6;
        int g = ((off >> 4) & 3) ^ ((row >> 1) & 3);
        gb[j] = Bt + (size_t)(n0 + row) * K + g * 8;
        loffB[j] = off;
    }

    auto stage = [&](int slot, int kt) {
        char* base = (char*)smem + slot * SLOT_B;
#pragma unroll
        for (int j = 0; j < 4; ++j)
            ld_lds16(ga[j] + kt * 32, base + loffA[j]);
#pragma unroll
        for (int j = 0; j < 2; ++j)
            ld_lds16(gb[j] + kt * 32, base + 16384 + loffB[j]);
    };

    f32x4 acc[8][4];
    const f32x4 z4 = {0.f, 0.f, 0.f, 0.f};
#pragma unroll
    for (int mi = 0; mi < 8; ++mi)
#pragma unroll
        for (int ni = 0; ni < 4; ++ni) acc[mi][ni] = z4;

    auto compute = [&](int slot) {
        const char* Ab = (const char*)smem + slot * SLOT_B;
        const char* Bb = Ab + 16384;
        bf16x8 bF[4];
#pragma unroll
        for (int ni = 0; ni < 4; ++ni) {
            int rB = wc * 64 + ni * 16 + i16;
            bF[ni] = *reinterpret_cast<const bf16x8*>(
                Bb + rB * 64 + ((quad ^ ((rB >> 1) & 3)) * 16));
        }
#pragma unroll
        for (int h = 0; h < 2; ++h) {
            bf16x8 aF[4];
#pragma unroll
            for (int mi = 0; mi < 4; ++mi) {
                int rA = wr * 128 + h * 64 + mi * 16 + i16;
                aF[mi] = *reinterpret_cast<const bf16x8*>(
                    Ab + rA * 64 + ((quad ^ ((rA >> 1) & 3)) * 16));
            }
            __builtin_amdgcn_s_setprio(1);
#pragma unroll
            for (int mi = 0; mi < 4; ++mi)
#pragma unroll
                for (int ni = 0; ni < 4; ++ni)
                    acc[h * 4 + mi][ni] = MFMA_BF16(aF[mi], bF[ni], acc[h * 4 + mi][ni]);
            __builtin_amdgcn_s_setprio(0);
        }
    };

    // prologue: K-tiles 0,1 into slots 0,1 (12 loads/thread); wait for K0
    stage(0, 0); stage(1, 1);
    asm volatile("s_waitcnt vmcnt(6)" ::: "memory");
    __builtin_amdgcn_s_barrier();
    asm volatile("" ::: "memory");

    // steady state: stage K(tt+2) into slot (tt+2)%3 = slot of K(tt-1), which
    // was fully read before the previous barrier (WAR-safe). End-of-iter wait
    // vmcnt(6) retires K(tt+1)'s 6 loads, keeps K(tt+2)'s 6 in flight.
    int cs = 0, ssl = 2;
    for (int tt = 0; tt < NT - 2; ++tt) {
        stage(ssl, tt + 2);
        compute(cs);
        asm volatile("s_waitcnt vmcnt(6)" ::: "memory");
        __builtin_amdgcn_s_barrier();
        asm volatile("" ::: "memory");
        cs  = (cs  == 2) ? 0 : cs  + 1;
        ssl = (ssl == 2) ? 0 : ssl + 1;
    }
    // tail: drain
    compute(cs);                               // K-tile NT-2
    asm volatile("s_waitcnt vmcnt(0)" ::: "memory");
    __builtin_amdgcn_s_barrier();
    asm volatile("" ::: "memory");
    cs = (cs == 2) ? 0 : cs + 1;
    compute(cs);                               // K-tile NT-1
    __syncthreads();   // all LDS reads done; ring becomes Cs bounce

    // ---------------- epilogue (one head per block: BN=128) ----------------
    unsigned short* Cs = smem;                 // 256x128 bf16 = 64KB (of 72KB)
    int which = n0 >> 11;                      // 0=q 1=k 2=v (uniform per block)
    int hh = (n0 & 2047) >> 7;                 // head
    const float* bp = (which == 0) ? b0 : ((which == 1) ? b1 : b2);
    int segn = n0 & 2047;
    int bb = m0 >> 11, s0 = m0 & 2047;

    if (which == 2) {
        // store transposed (d, s): Cs = [128 d][256 s], XOR-swizzled s-groups
#pragma unroll
        for (int mi = 0; mi < 8; ++mi)
#pragma unroll
            for (int ni = 0; ni < 4; ++ni) {
                int d = wc * 64 + ni * 16 + i16;
                float bv = bp[segn + d];
#pragma unroll
                for (int r = 0; r < 4; ++r) {
                    int sl = wr * 128 + mi * 16 + quad * 4 + r;
                    Cs[d * 256 + (((sl >> 3) ^ (d & 31)) * 8) + (sl & 7)] =
                        f2bf(acc[mi][ni][r] + bv);
                }
            }
        __syncthreads();
        unsigned short* vout = outp + 2 * QKV_SEG;
#pragma unroll
        for (int it = 0; it < 16; ++it) {
            int idx = it * 256 + t;            // [0,4096)
            int d = idx >> 5, sg = idx & 31;
            uint4 v = *reinterpret_cast<const uint4*>(
                &Cs[d * 256 + ((sg ^ (d & 31)) * 8)]);
            size_t oidx = (((size_t)(bb * NHEAD + hh)) * LDH + d) * S_LEN + s0 + sg * 8;
            *reinterpret_cast<uint4*>(vout + oidx) = v;
        }
    } else {
        // q/k: bounce raw acc+bias, then RoPE on store
#pragma unroll
        for (int mi = 0; mi < 8; ++mi)
#pragma unroll
            for (int ni = 0; ni < 4; ++ni) {
                int nl = wc * 64 + ni * 16 + i16;
                float bv = bp[segn + nl];
#pragma unroll
                for (int r = 0; r < 4; ++r) {
                    int ml = wr * 128 + mi * 16 + quad * 4 + r;
                    Cs[ml * 128 + nl] = f2bf(acc[mi][ni][r] + bv);
                }
            }
        __syncthreads();
        // fold softmax scale (1/sqrt(128)) * log2(e) into q
        float qscale = (which == 0) ? (0.08838834764831845f * 1.4426950408889634f) : 1.0f;
        unsigned short* qout = outp + (size_t)which * QKV_SEG;
#pragma unroll
        for (int it = 0; it < 16; ++it) {
            int idx = it * 256 + t;            // [0,4096)
            int row = idx >> 4, c16 = idx & 15;
            int mm = m0 + row;
            int ss = mm & 2047, bb2 = mm >> 11;
            int i8 = (c16 & 7) * 8;
            const unsigned short* crow = Cs + row * 128 + i8 * 2;
            uint4 w0 = *reinterpret_cast<const uint4*>(crow);
            uint4 w1 = *reinterpret_cast<const uint4*>(crow + 8);
            unsigned pw[8] = {w0.x, w0.y, w0.z, w0.w, w1.x, w1.y, w1.z, w1.w};
            float4 cA = *reinterpret_cast<const float4*>(&ctab[ss * 64 + i8]);
            float4 cB = *reinterpret_cast<const float4*>(&ctab[ss * 64 + i8 + 4]);
            float4 sA = *reinterpret_cast<const float4*>(&stab[ss * 64 + i8]);
            float4 sB = *reinterpret_cast<const float4*>(&stab[ss * 64 + i8 + 4]);
            float cv[8] = {cA.x, cA.y, cA.z, cA.w, cB.x, cB.y, cB.z, cB.w};
            float sv[8] = {sA.x, sA.y, sA.z, sA.w, sB.x, sB.y, sB.z, sB.w};
            bool hi = (c16 >= 8);
            unsigned short ov[8];
#pragma unroll
            for (int j = 0; j < 8; ++j) {
                float xe = bf2f((unsigned short)(pw[j] & 0xffff));
                float xo = bf2f((unsigned short)(pw[j] >> 16));
                float o = hi ? (xe * sv[j] + xo * cv[j]) : (xe * cv[j] - xo * sv[j]);
                ov[j] = f2bf(o * qscale);
            }
            size_t oidx = (((size_t)(bb2 * NHEAD + hh)) * S_LEN + ss) * LDH + c16 * 8;
            *reinterpret_cast<uint4*>(qout + oidx) =
                *reinterpret_cast<const uint4*>(ov);
        }
    }
}

// ---------------- flash attention v4: double-buffered staging ----------------
// anti-causal (keep k >= q); no-max softmax (exp2, scale folded into q);
// 128 q/block, 4 waves x 32 q; 64-key chunks; 1 barrier per chunk with
// async prefetch of chunk i+1 overlapping compute of chunk i.
__global__ __launch_bounds__(256, 2) void attn_kernel(
    const unsigned short* __restrict__ q,
    const unsigned short* __restrict__ k,
    const unsigned short* __restrict__ vt,
    unsigned short* __restrict__ att)
{
    __shared__ __attribute__((aligned(16))) unsigned short Ks[2][64 * 128];
    __shared__ __attribute__((aligned(16))) unsigned short Vs[2][128 * 64];
    __shared__ __attribute__((aligned(16))) unsigned short Ps[4][32 * 64];

    int bid = blockIdx.x;
    int second = bid >> 8;
    int p = bid & 255;
    int xb = second ? (15 - (p >> 5)) : (p >> 5);
    int bh = p & 31;
    int b = bh >> 4, h = bh & (NHEAD - 1);
    int q0 = xb * 128;

    int t = threadIdx.x, w = t >> 6, lane = t & 63;
    int i16 = lane & 15, quad = lane >> 4;
    int qbase = q0 + w * 32;

    bf16x8 qf[2][4];
#pragma unroll
    for (int qs = 0; qs < 2; ++qs) {
        const unsigned short* qrow = q + ((size_t)bh * S_LEN + qbase + qs * 16 + i16) * LDH;
#pragma unroll
        for (int c = 0; c < 4; ++c)
            qf[qs][c] = *reinterpret_cast<const bf16x8*>(qrow + c * 32 + quad * 8);
    }

    const f32x4 z4 = {0.f, 0.f, 0.f, 0.f};
    f32x4 o[2][8];
#pragma unroll
    for (int qs = 0; qs < 2; ++qs)
#pragma unroll
        for (int dt = 0; dt < 8; ++dt) o[qs][dt] = z4;
    float l_i[2] = {0.f, 0.f};

    const unsigned short* kbh  = k  + (size_t)bh * S_LEN * LDH;
    const unsigned short* vtbh = vt + (size_t)bh * LDH * S_LEN;
    unsigned short* PsW = Ps[w];

    auto stage = [&](int buf, int kk0) {
#pragma unroll
        for (int j = 0; j < 4; ++j) {
            int off = j * 4096 + w * 1024 + lane * 16;
            int key = off >> 8;
            int gk = ((off >> 4) & 15) ^ (key & 15);
            ld_lds16(&kbh[(size_t)(kk0 + key) * LDH + gk * 8], (char*)Ks[buf] + off);
            int d = off >> 7;
            int gv = ((off >> 4) & 7) ^ (d & 7);
            ld_lds16(&vtbh[(size_t)d * S_LEN + kk0 + gv * 8], (char*)Vs[buf] + off);
        }
    };

    stage(0, q0);
    int nch = (S_LEN - q0) >> 6;
    for (int ci = 0; ci < nch; ++ci) {
        __syncthreads();   // drains this wave's vmcnt -> buf[ci&1] ready; guards buf reuse
        if (ci + 1 < nch) stage((ci + 1) & 1, q0 + (ci + 1) * 64);
        int kk0 = q0 + ci * 64;
        if (kk0 + 64 <= qbase) continue;   // wave fully masked
        const unsigned short* Kb = Ks[ci & 1];
        const unsigned short* Vb = Vs[ci & 1];

        // QK^T: A=K (m=key), B=Q (n=q)
        f32x4 s[2][4];
#pragma unroll
        for (int qs = 0; qs < 2; ++qs)
#pragma unroll
            for (int kn = 0; kn < 4; ++kn) s[qs][kn] = z4;
#pragma unroll
        for (int c = 0; c < 4; ++c) {
            bf16x8 kf[4];
#pragma unroll
            for (int kn = 0; kn < 4; ++kn) {
                int key = kn * 16 + i16;
                int gs = (c * 4 + quad) ^ (key & 15);
                kf[kn] = *reinterpret_cast<const bf16x8*>((const char*)Kb + key * 256 + gs * 16);
            }
#pragma unroll
            for (int qs = 0; qs < 2; ++qs)
#pragma unroll
                for (int kn = 0; kn < 4; ++kn)
                    s[qs][kn] = MFMA_BF16(kf[kn], qf[qs][c], s[qs][kn]);
        }

        bool diag = (kk0 < qbase + 32);
#pragma unroll
        for (int qs = 0; qs < 2; ++qs) {
            int q_local = qs * 16 + i16;
            int qg = qbase + q_local;
#pragma unroll
            for (int kn = 0; kn < 4; ++kn) {
                int keyb = kk0 + kn * 16 + quad * 4;
                float pv[4];
                if (diag) {
#pragma unroll
                    for (int r = 0; r < 4; ++r)
                        pv[r] = (keyb + r >= qg) ? fexp2(s[qs][kn][r]) : 0.f;
                } else {
#pragma unroll
                    for (int r = 0; r < 4; ++r) pv[r] = fexp2(s[qs][kn][r]);
                }
                l_i[qs] += (pv[0] + pv[1]) + (pv[2] + pv[3]);
                unsigned lo = (unsigned)f2bf(pv[0]) | ((unsigned)f2bf(pv[1]) << 16);
                unsigned hi = (unsigned)f2bf(pv[2]) | ((unsigned)f2bf(pv[3]) << 16);
                int g = (kn * 2 + (quad >> 1)) ^ (q_local & 7);
                char* addr = (char*)PsW + q_local * 128 + g * 16 + (quad & 1) * 8;
                *reinterpret_cast<uint2*>(addr) = make_uint2(lo, hi);
            }
        }

        // PV: A=P (m=q), B=Vt (n=d); Ps per-wave -> no barrier
#pragma unroll
        for (int hh = 0; hh < 2; ++hh) {
            bf16x8 pf[2];
#pragma unroll
            for (int qs = 0; qs < 2; ++qs) {
                int q_local = qs * 16 + i16;
                int g = (hh * 4 + quad) ^ (q_local & 7);
                pf[qs] = *reinterpret_cast<const bf16x8*>((const char*)PsW + q_local * 128 + g * 16);
            }
#pragma unroll
            for (int dt = 0; dt < 8; ++dt) {
                int d = dt * 16 + i16;
                int gv = (hh * 4 + quad) ^ (d & 7);
                bf16x8 vf = *reinterpret_cast<const bf16x8*>((const char*)Vb + d * 128 + gv * 16);
                o[0][dt] = MFMA_BF16(pf[0], vf, o[0][dt]);
                o[1][dt] = MFMA_BF16(pf[1], vf, o[1][dt]);
            }
        }
    }

#pragma unroll
    for (int qs = 0; qs < 2; ++qs) {
        float lr = l_i[qs];
        lr += __shfl_xor(lr, 16);
        lr += __shfl_xor(lr, 32);
        l_i[qs] = lr;
    }
#pragma unroll
    for (int qs = 0; qs < 2; ++qs) {
#pragma unroll
        for (int r = 0; r < 4; ++r) {
            float lv = __shfl(l_i[qs], quad * 4 + r);
            float inv = 1.0f / lv;
            int qrow = qbase + qs * 16 + quad * 4 + r;
            unsigned short* orow = att + ((size_t)b * S_LEN + qrow) * DM + h * LDH;
#pragma unroll
            for (int dt = 0; dt < 8; ++dt)
                orow[dt * 16 + i16] = f2bf(o[qs][dt][r] * inv);
        }
    }
}

// ---------------- launcher ----------------
extern "C" void kernel_launch(void* const* d_in, const int* in_sizes, int n_in,
                              void* d_out, int out_size, void* d_ws, size_t ws_size,
                              hipStream_t stream) {
    const float* x  = (const float*)d_in[0];
    const float* Wq = (const float*)d_in[2];
    const float* bq = (const float*)d_in[3];
    const float* Wk = (const float*)d_in[4];
    const float* bk = (const float*)d_in[5];
    const float* Wv = (const float*)d_in[6];
    const float* bv = (const float*)d_in[7];
    const float* Wo = (const float*)d_in[8];
    const float* bo = (const float*)d_in[9];

    char* ws = (char*)d_ws;
    unsigned short* xb  = (unsigned short*)(ws);                  // 16 MB
    unsigned short* Wqt = (unsigned short*)(ws + 16777216);       // QKV weights contiguous
    unsigned short* Wkt = (unsigned short*)(ws + 25165824);
    unsigned short* Wvt = (unsigned short*)(ws + 33554432);
    unsigned short* Wot = (unsigned short*)(ws + 41943040);
    unsigned short* qkv = (unsigned short*)(ws + 50331648);       // q | k | v^T, 16 MB each
    unsigned short* att = (unsigned short*)(ws + 100663296);
    float* ctab = (float*)(ws + 117440512);                       // 512 KB
    float* stab = (float*)(ws + 117964800);                       // 512 KB

    convert_f32_bf16<<<8192, 256, 0, stream>>>(x, xb, (BATCH * S_LEN * DM) / 4);
    gen_tab<<<512, 256, 0, stream>>>(ctab, stab);
    wconv_t4<<<dim3(64, 64, 4), 256, 0, stream>>>(Wq, Wk, Wv, Wo, Wqt, Wkt, Wvt, Wot);

    // fused QKV projection + RoPE + V-transpose: M=4096, N=6144, K=2048
    gemm_qkv_v2<<<dim3(48, 16), 256, 0, stream>>>(
        xb, Wqt, bq, bk, bv, ctab, stab, qkv);

    attn_kernel<<<512, 256, 0, stream>>>(qkv, qkv + QKV_SEG, qkv + 2 * QKV_SEG, att);

    // output projection: M=4096, N=2048, K=2048, fp32 out
    gemm_bf16_out<<<dim3(DM / 128, (BATCH * S_LEN) / 128), 256, 0, stream>>>(
        att, Wot, bo, (float*)d_out);
}

// Round 6
// 383.082 us; speedup vs baseline: 1.0802x; 1.0338x over previous
//
#include <hip/hip_runtime.h>
#include <math.h>

typedef __bf16 bf16x8 __attribute__((ext_vector_type(8)));
typedef float f32x4 __attribute__((ext_vector_type(4)));

#define MFMA_BF16(a,b,c) __builtin_amdgcn_mfma_f32_16x16x32_bf16((a),(b),(c),0,0,0)

static constexpr int S_LEN = 2048;
static constexpr int DM    = 2048;
static constexpr int NHEAD = 16;
static constexpr int LDH   = 128;
static constexpr int BATCH = 2;
static constexpr size_t QKV_SEG = (size_t)BATCH * NHEAD * S_LEN * LDH;  // elems per q/k/v

__device__ __forceinline__ unsigned short f2bf(float f) {
    unsigned u = __float_as_uint(f);
    u += 0x7fffu + ((u >> 16) & 1u);
    return (unsigned short)(u >> 16);
}
__device__ __forceinline__ float bf2f(unsigned short h) {
    return __uint_as_float(((unsigned)h) << 16);
}
__device__ __forceinline__ float fexp2(float x) { return exp2f(x); }

__device__ __forceinline__ void ld_lds16(const void* g, void* l) {
    __builtin_amdgcn_global_load_lds(
        (const __attribute__((address_space(1))) unsigned int*)g,
        (__attribute__((address_space(3))) unsigned int*)l, 16, 0, 0);
}

// ---------------- fused preprocessing: x->bf16 | rope tables | 4x weight transpose ----------------
// Single kernel replaces convert_f32_bf16 + gen_tab + wconv_t4 (saves 2 launch/drain gaps).
// Blocks [0,8192): convert; [8192,8704): tables; [8704,25088): weight transpose.
__global__ void prep_all(const float* __restrict__ x, unsigned short* __restrict__ xb,
                         float* __restrict__ ct, float* __restrict__ st,
                         const float* __restrict__ W0, const float* __restrict__ W1,
                         const float* __restrict__ W2, const float* __restrict__ W3,
                         unsigned short* __restrict__ O0, unsigned short* __restrict__ O1,
                         unsigned short* __restrict__ O2, unsigned short* __restrict__ O3) {
    __shared__ unsigned short tile[32][33];
    int bid = blockIdx.x;
    int t = threadIdx.x;
    if (bid < 8192) {
        int idx = bid * 256 + t;                       // n4 = 2*2048*2048/4 = 2097152
        float4 v = reinterpret_cast<const float4*>(x)[idx];
        unsigned lo = (unsigned)f2bf(v.x) | ((unsigned)f2bf(v.y) << 16);
        unsigned hi = (unsigned)f2bf(v.z) | ((unsigned)f2bf(v.w) << 16);
        reinterpret_cast<uint2*>(xb)[idx] = make_uint2(lo, hi);
    } else if (bid < 8704) {
        int i = t & 63;
        int s = (bid - 8192) * 4 + (t >> 6);
        float freq = (float)exp(-(double)(2 * i) / 128.0 * 9.210340371976184);
        float a = (float)s * freq;
        ct[s * 64 + i] = cosf(a);
        st[s * 64 + i] = sinf(a);
    } else {
        int wid = bid - 8704;                          // [0,16384)
        int z = wid >> 12;
        int rem = wid & 4095;
        int k0 = (rem >> 6) * 32;
        int n0 = (rem & 63) * 32;
        const float* W = (z == 0) ? W0 : (z == 1) ? W1 : (z == 2) ? W2 : W3;
        unsigned short* Wt = (z == 0) ? O0 : (z == 1) ? O1 : (z == 2) ? O2 : O3;
        int ir = t >> 3, ic = (t & 7) * 4;
        float4 v = *reinterpret_cast<const float4*>(&W[(size_t)(k0 + ir) * DM + n0 + ic]);
        tile[ir][ic + 0] = f2bf(v.x);
        tile[ir][ic + 1] = f2bf(v.y);
        tile[ir][ic + 2] = f2bf(v.z);
        tile[ir][ic + 3] = f2bf(v.w);
        __syncthreads();
        unsigned lo = (unsigned)tile[ic + 0][ir] | ((unsigned)tile[ic + 1][ir] << 16);
        unsigned hi = (unsigned)tile[ic + 2][ir] | ((unsigned)tile[ic + 3][ir] << 16);
        *reinterpret_cast<uint2*>(&Wt[(size_t)(n0 + ir) * DM + k0 + ic]) = make_uint2(lo, hi);
    }
}

// ---------------- 256x128-tile out-proj GEMM: 3-ring counted vmcnt, fp32 out + bias ----------------
// M=4096, N=2048, K=2048. Same proven K-loop as gemm_qkv_v2. Grid 16x16 = 256
// blocks = 1/CU, single round, full machine. Direct fp32 epilogue (no bounce).
__global__ __launch_bounds__(256, 2) void gemm_out_v2(
    const unsigned short* __restrict__ A,
    const unsigned short* __restrict__ Bt,
    const float* __restrict__ b0,
    float* __restrict__ outp)
{
    constexpr int K  = DM;
    constexpr int NT = K / 32;
    constexpr int SLOT_B = 24576;
    __shared__ __attribute__((aligned(16))) unsigned short smem[36864];  // 72 KB

    int t = threadIdx.x, lane = t & 63, w = t >> 6;
    int i16 = lane & 15, quad = lane >> 4;
    int wc = w & 1, wr = w >> 1;

    // XCD-bijective swizzle: 256 blocks = 8 XCDs x 32 (2-wide N band x 16 M)
    int flat = blockIdx.y * 16 + blockIdx.x;
    int xcd = flat & 7, r8 = flat >> 3;          // r8 in [0,32)
    int nbx = xcd * 2 + (r8 >> 4);
    int nby = r8 & 15;
    int m0 = nby * 256, n0 = nbx * 128;

    const unsigned short* ga[4];
    const unsigned short* gb[2];
    int loffA[4], loffB[2];
#pragma unroll
    for (int j = 0; j < 4; ++j) {
        int off = j * 4096 + t * 16;
        int row = off >> 6;
        int g = ((off >> 4) & 3) ^ ((row >> 1) & 3);
        ga[j] = A + (size_t)(m0 + row) * K + g * 8;
        loffA[j] = off;
    }
#pragma unroll
    for (int j = 0; j < 2; ++j) {
        int off = j * 4096 + t * 16;
        int row = off >> 6;
        int g = ((off >> 4) & 3) ^ ((row >> 1) & 3);
        gb[j] = Bt + (size_t)(n0 + row) * K + g * 8;
        loffB[j] = off;
    }

    auto stage = [&](int slot, int kt) {
        char* base = (char*)smem + slot * SLOT_B;
#pragma unroll
        for (int j = 0; j < 4; ++j)
            ld_lds16(ga[j] + kt * 32, base + loffA[j]);
#pragma unroll
        for (int j = 0; j < 2; ++j)
            ld_lds16(gb[j] + kt * 32, base + 16384 + loffB[j]);
    };

    f32x4 acc[8][4];
    const f32x4 z4 = {0.f, 0.f, 0.f, 0.f};
#pragma unroll
    for (int mi = 0; mi < 8; ++mi)
#pragma unroll
        for (int ni = 0; ni < 4; ++ni) acc[mi][ni] = z4;

    auto compute = [&](int slot) {
        const char* Ab = (const char*)smem + slot * SLOT_B;
        const char* Bb = Ab + 16384;
        bf16x8 bF[4];
#pragma unroll
        for (int ni = 0; ni < 4; ++ni) {
            int rB = wc * 64 + ni * 16 + i16;
            bF[ni] = *reinterpret_cast<const bf16x8*>(
                Bb + rB * 64 + ((quad ^ ((rB >> 1) & 3)) * 16));
        }
#pragma unroll
        for (int h = 0; h < 2; ++h) {
            bf16x8 aF[4];
#pragma unroll
            for (int mi = 0; mi < 4; ++mi) {
                int rA = wr * 128 + h * 64 + mi * 16 + i16;
                aF[mi] = *reinterpret_cast<const bf16x8*>(
                    Ab + rA * 64 + ((quad ^ ((rA >> 1) & 3)) * 16));
            }
            __builtin_amdgcn_s_setprio(1);
#pragma unroll
            for (int mi = 0; mi < 4; ++mi)
#pragma unroll
                for (int ni = 0; ni < 4; ++ni)
                    acc[h * 4 + mi][ni] = MFMA_BF16(aF[mi], bF[ni], acc[h * 4 + mi][ni]);
            __builtin_amdgcn_s_setprio(0);
        }
    };

    stage(0, 0); stage(1, 1);
    asm volatile("s_waitcnt vmcnt(6)" ::: "memory");
    __builtin_amdgcn_s_barrier();
    asm volatile("" ::: "memory");

    int cs = 0, ssl = 2;
    for (int tt = 0; tt < NT - 2; ++tt) {
        stage(ssl, tt + 2);
        compute(cs);
        asm volatile("s_waitcnt vmcnt(6)" ::: "memory");
        __builtin_amdgcn_s_barrier();
        asm volatile("" ::: "memory");
        cs  = (cs  == 2) ? 0 : cs  + 1;
        ssl = (ssl == 2) ? 0 : ssl + 1;
    }
    compute(cs);
    asm volatile("s_waitcnt vmcnt(0)" ::: "memory");
    __builtin_amdgcn_s_barrier();
    asm volatile("" ::: "memory");
    cs = (cs == 2) ? 0 : cs + 1;
    compute(cs);

    // fp32 epilogue straight from regs
#pragma unroll
    for (int mi = 0; mi < 8; ++mi)
#pragma unroll
        for (int ni = 0; ni < 4; ++ni) {
            int nn = n0 + wc * 64 + ni * 16 + i16;
            float bv = b0[nn];
#pragma unroll
            for (int r = 0; r < 4; ++r) {
                int mm = m0 + wr * 128 + mi * 16 + quad * 4 + r;
                outp[(size_t)mm * DM + nn] = acc[mi][ni][r] + bv;
            }
        }
}

// ---------------- 256x128-tile fused QKV GEMM: 3-deep ring, counted vmcnt ----------------
// M=4096, N=6144, K=2048. 256 threads = 4 waves (2M x 2N), per-wave 128x64 out.
// BK=32; LDS = 3 ring slots x (A 16KB | B 8KB) = 72KB -> 2 blocks/CU.
// Grid 48x16 = 768 blocks; stage runs 2 K-tiles ahead; steady-state vmcnt(6).
__global__ __launch_bounds__(256, 2) void gemm_qkv_v2(
    const unsigned short* __restrict__ A,
    const unsigned short* __restrict__ Bt,
    const float* __restrict__ b0, const float* __restrict__ b1,
    const float* __restrict__ b2,
    const float* __restrict__ ctab, const float* __restrict__ stab,
    unsigned short* __restrict__ outp)
{
    constexpr int K  = DM;
    constexpr int NT = K / 32;     // 64 K-tiles
    constexpr int SLOT_B = 24576;  // bytes per ring slot (A 16KB + B 8KB)
    __shared__ __attribute__((aligned(16))) unsigned short smem[36864];  // 72 KB

    int t = threadIdx.x, lane = t & 63, w = t >> 6;
    int i16 = lane & 15, quad = lane >> 4;
    int wc = w & 1, wr = w >> 1;

    // XCD-bijective swizzle: 768 blocks = 8 XCDs x 96 (6-wide N band x 16 M)
    int flat = blockIdx.y * 48 + blockIdx.x;
    int xcd = flat & 7, r8 = flat >> 3;          // r8 in [0,96)
    int nbx = xcd * 6 + (r8 >> 4);
    int nby = r8 & 15;
    int m0 = nby * 256, n0 = nbx * 128;

    const unsigned short* ga[4];
    const unsigned short* gb[2];
    int loffA[4], loffB[2];
#pragma unroll
    for (int j = 0; j < 4; ++j) {
        int off = j * 4096 + t * 16;              // within 16KB A tile
        int row = off >> 6;                       // 64B rows (32 bf16)
        int g = ((off >> 4) & 3) ^ ((row >> 1) & 3);
        ga[j] = A + (size_t)(m0 + row) * K + g * 8;
        loffA[j] = off;
    }
#pragma unroll
    for (int j = 0; j < 2; ++j) {
        int off = j * 4096 + t * 16;              // within 8KB B tile
        int row = off >> 6;
        int g = ((off >> 4) & 3) ^ ((row >> 1) & 3);
        gb[j] = Bt + (size_t)(n0 + row) * K + g * 8;
        loffB[j] = off;
    }

    auto stage = [&](int slot, int kt) {
        char* base = (char*)smem + slot * SLOT_B;
#pragma unroll
        for (int j = 0; j < 4; ++j)
            ld_lds16(ga[j] + kt * 32, base + loffA[j]);
#pragma unroll
        for (int j = 0; j < 2; ++j)
            ld_lds16(gb[j] + kt * 32, base + 16384 + loffB[j]);
    };

    f32x4 acc[8][4];
    const f32x4 z4 = {0.f, 0.f, 0.f, 0.f};
#pragma unroll
    for (int mi = 0; mi < 8; ++mi)
#pragma unroll
        for (int ni = 0; ni < 4; ++ni) acc[mi][ni] = z4;

    auto compute = [&](int slot) {
        const char* Ab = (const char*)smem + slot * SLOT_B;
        const char* Bb = Ab + 16384;
        bf16x8 bF[4];
#pragma unroll
        for (int ni = 0; ni < 4; ++ni) {
            int rB = wc * 64 + ni * 16 + i16;
            bF[ni] = *reinterpret_cast<const bf16x8*>(
                Bb + rB * 64 + ((quad ^ ((rB >> 1) & 3)) * 16));
        }
#pragma unroll
        for (int h = 0; h < 2; ++h) {
            bf16x8 aF[4];
#pragma unroll
            for (int mi = 0; mi < 4; ++mi) {
                int rA = wr * 128 + h * 64 + mi * 16 + i16;
                aF[mi] = *reinterpret_cast<const bf16x8*>(
                    Ab + rA * 64 + ((quad ^ ((rA >> 1) & 3)) * 16));
            }
            __builtin_amdgcn_s_setprio(1);
#pragma unroll
            for (int mi = 0; mi < 4; ++mi)
#pragma unroll
                for (int ni = 0; ni < 4; ++ni)
                    acc[h * 4 + mi][ni] = MFMA_BF16(aF[mi], bF[ni], acc[h * 4 + mi][ni]);
            __builtin_amdgcn_s_setprio(0);
        }
    };

    stage(0, 0); stage(1, 1);
    asm volatile("s_waitcnt vmcnt(6)" ::: "memory");
    __builtin_amdgcn_s_barrier();
    asm volatile("" ::: "memory");

    int cs = 0, ssl = 2;
    for (int tt = 0; tt < NT - 2; ++tt) {
        stage(ssl, tt + 2);
        compute(cs);
        asm volatile("s_waitcnt vmcnt(6)" ::: "memory");
        __builtin_amdgcn_s_barrier();
        asm volatile("" ::: "memory");
        cs  = (cs  == 2) ? 0 : cs  + 1;
        ssl = (ssl == 2) ? 0 : ssl + 1;
    }
    compute(cs);                               // K-tile NT-2
    asm volatile("s_waitcnt vmcnt(0)" ::: "memory");
    __builtin_amdgcn_s_barrier();
    asm volatile("" ::: "memory");
    cs = (cs == 2) ? 0 : cs + 1;
    compute(cs);                               // K-tile NT-1
    __syncthreads();   // all LDS reads done; ring becomes Cs bounce

    // ---------------- epilogue (one head per block: BN=128) ----------------
    unsigned short* Cs = smem;                 // 256x128 bf16 = 64KB (of 72KB)
    int which = n0 >> 11;                      // 0=q 1=k 2=v (uniform per block)
    int hh = (n0 & 2047) >> 7;                 // head
    const float* bp = (which == 0) ? b0 : ((which == 1) ? b1 : b2);
    int segn = n0 & 2047;
    int bb = m0 >> 11, s0 = m0 & 2047;

    if (which == 2) {
        // store transposed (d, s): Cs = [128 d][256 s], XOR-swizzled s-groups
#pragma unroll
        for (int mi = 0; mi < 8; ++mi)
#pragma unroll
            for (int ni = 0; ni < 4; ++ni) {
                int d = wc * 64 + ni * 16 + i16;
                float bv = bp[segn + d];
#pragma unroll
                for (int r = 0; r < 4; ++r) {
                    int sl = wr * 128 + mi * 16 + quad * 4 + r;
                    Cs[d * 256 + (((sl >> 3) ^ (d & 31)) * 8) + (sl & 7)] =
                        f2bf(acc[mi][ni][r] + bv);
                }
            }
        __syncthreads();
        unsigned short* vout = outp + 2 * QKV_SEG;
#pragma unroll
        for (int it = 0; it < 16; ++it) {
            int idx = it * 256 + t;            // [0,4096)
            int d = idx >> 5, sg = idx & 31;
            uint4 v = *reinterpret_cast<const uint4*>(
                &Cs[d * 256 + ((sg ^ (d & 31)) * 8)]);
            size_t oidx = (((size_t)(bb * NHEAD + hh)) * LDH + d) * S_LEN + s0 + sg * 8;
            *reinterpret_cast<uint4*>(vout + oidx) = v;
        }
    } else {
        // q/k: bounce raw acc+bias, then RoPE on store
#pragma unroll
        for (int mi = 0; mi < 8; ++mi)
#pragma unroll
            for (int ni = 0; ni < 4; ++ni) {
                int nl = wc * 64 + ni * 16 + i16;
                float bv = bp[segn + nl];
#pragma unroll
                for (int r = 0; r < 4; ++r) {
                    int ml = wr * 128 + mi * 16 + quad * 4 + r;
                    Cs[ml * 128 + nl] = f2bf(acc[mi][ni][r] + bv);
                }
            }
        __syncthreads();
        // fold softmax scale (1/sqrt(128)) * log2(e) into q
        float qscale = (which == 0) ? (0.08838834764831845f * 1.4426950408889634f) : 1.0f;
        unsigned short* qout = outp + (size_t)which * QKV_SEG;
#pragma unroll
        for (int it = 0; it < 16; ++it) {
            int idx = it * 256 + t;            // [0,4096)
            int row = idx >> 4, c16 = idx & 15;
            int mm = m0 + row;
            int ss = mm & 2047, bb2 = mm >> 11;
            int i8 = (c16 & 7) * 8;
            const unsigned short* crow = Cs + row * 128 + i8 * 2;
            uint4 w0 = *reinterpret_cast<const uint4*>(crow);
            uint4 w1 = *reinterpret_cast<const uint4*>(crow + 8);
            unsigned pw[8] = {w0.x, w0.y, w0.z, w0.w, w1.x, w1.y, w1.z, w1.w};
            float4 cA = *reinterpret_cast<const float4*>(&ctab[ss * 64 + i8]);
            float4 cB = *reinterpret_cast<const float4*>(&ctab[ss * 64 + i8 + 4]);
            float4 sA = *reinterpret_cast<const float4*>(&stab[ss * 64 + i8]);
            float4 sB = *reinterpret_cast<const float4*>(&stab[ss * 64 + i8 + 4]);
            float cv[8] = {cA.x, cA.y, cA.z, cA.w, cB.x, cB.y, cB.z, cB.w};
            float sv[8] = {sA.x, sA.y, sA.z, sA.w, sB.x, sB.y, sB.z, sB.w};
            bool hi = (c16 >= 8);
            unsigned short ov[8];
#pragma unroll
            for (int j = 0; j < 8; ++j) {
                float xe = bf2f((unsigned short)(pw[j] & 0xffff));
                float xo = bf2f((unsigned short)(pw[j] >> 16));
                float o = hi ? (xe * sv[j] + xo * cv[j]) : (xe * cv[j] - xo * sv[j]);
                ov[j] = f2bf(o * qscale);
            }
            size_t oidx = (((size_t)(bb2 * NHEAD + hh)) * S_LEN + ss) * LDH + c16 * 8;
            *reinterpret_cast<uint4*>(qout + oidx) =
                *reinterpret_cast<const uint4*>(ov);
        }
    }
}

// ---------------- flash attention v4: double-buffered staging + setprio ----------------
// anti-causal (keep k >= q); no-max softmax (exp2, scale folded into q);
// 128 q/block, 4 waves x 32 q; 64-key chunks; 1 barrier per chunk with
// async prefetch of chunk i+1 overlapping compute of chunk i.
__global__ __launch_bounds__(256, 2) void attn_kernel(
    const unsigned short* __restrict__ q,
    const unsigned short* __restrict__ k,
    const unsigned short* __restrict__ vt,
    unsigned short* __restrict__ att)
{
    __shared__ __attribute__((aligned(16))) unsigned short Ks[2][64 * 128];
    __shared__ __attribute__((aligned(16))) unsigned short Vs[2][128 * 64];
    __shared__ __attribute__((aligned(16))) unsigned short Ps[4][32 * 64];

    int bid = blockIdx.x;
    int second = bid >> 8;
    int p = bid & 255;
    int xb = second ? (15 - (p >> 5)) : (p >> 5);
    int bh = p & 31;
    int b = bh >> 4, h = bh & (NHEAD - 1);
    int q0 = xb * 128;

    int t = threadIdx.x, w = t >> 6, lane = t & 63;
    int i16 = lane & 15, quad = lane >> 4;
    int qbase = q0 + w * 32;

    bf16x8 qf[2][4];
#pragma unroll
    for (int qs = 0; qs < 2; ++qs) {
        const unsigned short* qrow = q + ((size_t)bh * S_LEN + qbase + qs * 16 + i16) * LDH;
#pragma unroll
        for (int c = 0; c < 4; ++c)
            qf[qs][c] = *reinterpret_cast<const bf16x8*>(qrow + c * 32 + quad * 8);
    }

    const f32x4 z4 = {0.f, 0.f, 0.f, 0.f};
    f32x4 o[2][8];
#pragma unroll
    for (int qs = 0; qs < 2; ++qs)
#pragma unroll
        for (int dt = 0; dt < 8; ++dt) o[qs][dt] = z4;
    float l_i[2] = {0.f, 0.f};

    const unsigned short* kbh  = k  + (size_t)bh * S_LEN * LDH;
    const unsigned short* vtbh = vt + (size_t)bh * LDH * S_LEN;
    unsigned short* PsW = Ps[w];

    auto stage = [&](int buf, int kk0) {
#pragma unroll
        for (int j = 0; j < 4; ++j) {
            int off = j * 4096 + w * 1024 + lane * 16;
            int key = off >> 8;
            int gk = ((off >> 4) & 15) ^ (key & 15);
            ld_lds16(&kbh[(size_t)(kk0 + key) * LDH + gk * 8], (char*)Ks[buf] + off);
            int d = off >> 7;
            int gv = ((off >> 4) & 7) ^ (d & 7);
            ld_lds16(&vtbh[(size_t)d * S_LEN + kk0 + gv * 8], (char*)Vs[buf] + off);
        }
    };

    stage(0, q0);
    int nch = (S_LEN - q0) >> 6;
    for (int ci = 0; ci < nch; ++ci) {
        __syncthreads();   // drains this wave's vmcnt -> buf[ci&1] ready; guards buf reuse
        if (ci + 1 < nch) stage((ci + 1) & 1, q0 + (ci + 1) * 64);
        int kk0 = q0 + ci * 64;
        if (kk0 + 64 <= qbase) continue;   // wave fully masked
        const unsigned short* Kb = Ks[ci & 1];
        const unsigned short* Vb = Vs[ci & 1];

        // QK^T: A=K (m=key), B=Q (n=q)
        f32x4 s[2][4];
#pragma unroll
        for (int qs = 0; qs < 2; ++qs)
#pragma unroll
            for (int kn = 0; kn < 4; ++kn) s[qs][kn] = z4;
#pragma unroll
        for (int c = 0; c < 4; ++c) {
            bf16x8 kf[4];
#pragma unroll
            for (int kn = 0; kn < 4; ++kn) {
                int key = kn * 16 + i16;
                int gs = (c * 4 + quad) ^ (key & 15);
                kf[kn] = *reinterpret_cast<const bf16x8*>((const char*)Kb + key * 256 + gs * 16);
            }
            __builtin_amdgcn_s_setprio(1);
#pragma unroll
            for (int qs = 0; qs < 2; ++qs)
#pragma unroll
                for (int kn = 0; kn < 4; ++kn)
                    s[qs][kn] = MFMA_BF16(kf[kn], qf[qs][c], s[qs][kn]);
            __builtin_amdgcn_s_setprio(0);
        }

        bool diag = (kk0 < qbase + 32);
#pragma unroll
        for (int qs = 0; qs < 2; ++qs) {
            int q_local = qs * 16 + i16;
            int qg = qbase + q_local;
#pragma unroll
            for (int kn = 0; kn < 4; ++kn) {
                int keyb = kk0 + kn * 16 + quad * 4;
                float pv[4];
                if (diag) {
#pragma unroll
                    for (int r = 0; r < 4; ++r)
                        pv[r] = (keyb + r >= qg) ? fexp2(s[qs][kn][r]) : 0.f;
                } else {
#pragma unroll
                    for (int r = 0; r < 4; ++r) pv[r] = fexp2(s[qs][kn][r]);
                }
                l_i[qs] += (pv[0] + pv[1]) + (pv[2] + pv[3]);
                unsigned lo = (unsigned)f2bf(pv[0]) | ((unsigned)f2bf(pv[1]) << 16);
                unsigned hi = (unsigned)f2bf(pv[2]) | ((unsigned)f2bf(pv[3]) << 16);
                int g = (kn * 2 + (quad >> 1)) ^ (q_local & 7);
                char* addr = (char*)PsW + q_local * 128 + g * 16 + (quad & 1) * 8;
                *reinterpret_cast<uint2*>(addr) = make_uint2(lo, hi);
            }
        }

        // PV: A=P (m=q), B=Vt (n=d); Ps per-wave -> no barrier
#pragma unroll
        for (int hh = 0; hh < 2; ++hh) {
            bf16x8 pf[2];
#pragma unroll
            for (int qs = 0; qs < 2; ++qs) {
                int q_local = qs * 16 + i16;
                int g = (hh * 4 + quad) ^ (q_local & 7);
                pf[qs] = *reinterpret_cast<const bf16x8*>((const char*)PsW + q_local * 128 + g * 16);
            }
            __builtin_amdgcn_s_setprio(1);
#pragma unroll
            for (int dt = 0; dt < 8; ++dt) {
                int d = dt * 16 + i16;
                int gv = (hh * 4 + quad) ^ (d & 7);
                bf16x8 vf = *reinterpret_cast<const bf16x8*>((const char*)Vb + d * 128 + gv * 16);
                o[0][dt] = MFMA_BF16(pf[0], vf, o[0][dt]);
                o[1][dt] = MFMA_BF16(pf[1], vf, o[1][dt]);
            }
            __builtin_amdgcn_s_setprio(0);
        }
    }

#pragma unroll
    for (int qs = 0; qs < 2; ++qs) {
        float lr = l_i[qs];
        lr += __shfl_xor(lr, 16);
        lr += __shfl_xor(lr, 32);
        l_i[qs] = lr;
    }
#pragma unroll
    for (int qs = 0; qs < 2; ++qs) {
#pragma unroll
        for (int r = 0; r < 4; ++r) {
            float lv = __shfl(l_i[qs], quad * 4 + r);
            float inv = 1.0f / lv;
            int qrow = qbase + qs * 16 + quad * 4 + r;
            unsigned short* orow = att + ((size_t)b * S_LEN + qrow) * DM + h * LDH;
#pragma unroll
            for (int dt = 0; dt < 8; ++dt)
                orow[dt * 16 + i16] = f2bf(o[qs][dt][r] * inv);
        }
    }
}

// ---------------- launcher ----------------
extern "C" void kernel_launch(void* const* d_in, const int* in_sizes, int n_in,
                              void* d_out, int out_size, void* d_ws, size_t ws_size,
                              hipStream_t stream) {
    const float* x  = (const float*)d_in[0];
    const float* Wq = (const float*)d_in[2];
    const float* bq = (const float*)d_in[3];
    const float* Wk = (const float*)d_in[4];
    const float* bk = (const float*)d_in[5];
    const float* Wv = (const float*)d_in[6];
    const float* bv = (const float*)d_in[7];
    const float* Wo = (const float*)d_in[8];
    const float* bo = (const float*)d_in[9];

    char* ws = (char*)d_ws;
    unsigned short* xb  = (unsigned short*)(ws);                  // 16 MB
    unsigned short* Wqt = (unsigned short*)(ws + 16777216);       // QKV weights contiguous
    unsigned short* Wkt = (unsigned short*)(ws + 25165824);
    unsigned short* Wvt = (unsigned short*)(ws + 33554432);
    unsigned short* Wot = (unsigned short*)(ws + 41943040);
    unsigned short* qkv = (unsigned short*)(ws + 50331648);       // q | k | v^T, 16 MB each
    unsigned short* att = (unsigned short*)(ws + 100663296);
    float* ctab = (float*)(ws + 117440512);                       // 512 KB
    float* stab = (float*)(ws + 117964800);                       // 512 KB

    // fused preprocessing (convert + tables + 4x weight transpose)
    prep_all<<<25088, 256, 0, stream>>>(x, xb, ctab, stab,
                                        Wq, Wk, Wv, Wo, Wqt, Wkt, Wvt, Wot);

    // fused QKV projection + RoPE + V-transpose: M=4096, N=6144, K=2048
    gemm_qkv_v2<<<dim3(48, 16), 256, 0, stream>>>(
        xb, Wqt, bq, bk, bv, ctab, stab, qkv);

    attn_kernel<<<512, 256, 0, stream>>>(qkv, qkv + QKV_SEG, qkv + 2 * QKV_SEG, att);

    // output projection: M=4096, N=2048, K=2048, fp32 out
    gemm_out_v2<<<dim3(16, 16), 256, 0, stream>>>(att, Wot, bo, (float*)d_out);
}